// Round 16
// baseline (64.777 us; speedup 1.0000x reference)
//
#include <hip/hip_runtime.h>
#include <hip/hip_bf16.h>

typedef float f32x4 __attribute__((ext_vector_type(4)));
typedef _Float16 f16x8 __attribute__((ext_vector_type(8)));
typedef int   int4v  __attribute__((ext_vector_type(4)));
typedef int   int2v  __attribute__((ext_vector_type(2)));

#define LOG2E 1.44269504088896340736f
#define LN2   0.693147180559945309417f
#define EXP2R(x) __builtin_amdgcn_exp2f(x)   // raw v_exp_f32
#define LOG2R(x) __builtin_amdgcn_logf(x)    // raw v_log_f32 (log2)

// ---------------------------------------------------------------------------
// Kernel 1: q,k (-> fp16), v (f32), W[row,f] = sum_d t2[126-f-d]*k[row,d] (fp16).
// Publishes t2 scaler table to global (t2g) for k_score's scalar loads.
// 4 rows per block, 256 blocks, 384 threads = 6 waves.
// ---------------------------------------------------------------------------
__global__ __launch_bounds__(384) void k_qkv(
    const float* __restrict__ x,
    const float* __restrict__ Wq, const float* __restrict__ bq,
    const float* __restrict__ Wk, const float* __restrict__ bk,
    const float* __restrict__ Wv, const float* __restrict__ bv,
    _Float16* __restrict__ qf, _Float16* __restrict__ kf,
    _Float16* __restrict__ wf, float* __restrict__ vout,
    float* __restrict__ t2g)
{
    const int row0 = blockIdx.x * 4;           // rows = b*512 + i, [0,1024)
    __shared__ __align__(16) float xr[4][512];
    __shared__ __align__(16) float klds[4][64];
    __shared__ __align__(16) float t2s[128];
    const int tid = threadIdx.x;

    for (int i = tid; i < 512; i += 384)       // 4 rows * 512 f32 = 512 float4
        ((f32x4*)&xr[0][0])[i] = ((const f32x4*)(x + (size_t)row0 * 512))[i];
    if (tid < 128) { // scaler table by shift s; t2s[127] = 0 (phantom slot)
        int s = tid, t = 126 - s;
        float nd = (t < 64) ? (float)(t + 1) : (float)(127 - t);
        float val = (s < 127) ? ((float)(t + 2) / nd) * LOG2E : 0.0f;
        t2s[s] = val;
        t2g[s] = val;       // idempotent publish
    }
    __syncthreads();

    const int w = tid >> 6, f = tid & 63;
    const int m = w >> 1, rp = (w & 1) * 2;    // matrix, row-pair base
    const float* W    = (m == 0) ? Wq : (m == 1) ? Wk : Wv;
    const float bias  = ((m == 0) ? bq : (m == 1) ? bk : bv)[f];
    float a0 = bias, a1 = bias;
    #pragma unroll 16
    for (int d = 0; d < 512; ++d) {
        float wv = W[(size_t)d * 64 + f];
        a0 = fmaf(xr[rp][d], wv, a0);
        a1 = fmaf(xr[rp + 1][d], wv, a1);
    }
    if (m == 0) {
        qf[(size_t)(row0 + rp) * 64 + f]     = (_Float16)a0;
        qf[(size_t)(row0 + rp + 1) * 64 + f] = (_Float16)a1;
    } else if (m == 1) {
        kf[(size_t)(row0 + rp) * 64 + f]     = (_Float16)a0;
        kf[(size_t)(row0 + rp + 1) * 64 + f] = (_Float16)a1;
        klds[rp][f] = a0; klds[rp + 1][f] = a1;
    } else {
        vout[(size_t)(row0 + rp) * 64 + f]     = a0;
        vout[(size_t)(row0 + rp + 1) * 64 + f] = a1;
    }
    __syncthreads();
    if (m == 2) { // wf[row,f] = sum_d t2s[126-f-d]*k[row,d], rows rp..rp+1
        float w0 = 0.f, w1 = 0.f;
        #pragma unroll 8
        for (int d = 0; d < 64; ++d) {
            float t = t2s[126 - f - d];
            w0 = fmaf(t, klds[rp][d], w0);
            w1 = fmaf(t, klds[rp + 1][d], w1);
        }
        wf[(size_t)(row0 + rp) * 64 + f]     = (_Float16)w0;
        wf[(size_t)(row0 + rp + 1) * 64 + f] = (_Float16)w1;
    }
}

// ---------------------------------------------------------------------------
// Kernel 2: per (b, i-tile 16, j-tile 16): 4 waves x 32 shift-slots, BATCH-4.
// Live-set engineered <=64 VGPR for the 8-waves/SIMD occupancy bin (m69:
// occupancy steps at VGPR 64/128/256): af[2]=8, dk[2][6]=12, av[4][4]=16,
// mh/se=8, t2 in SGPRs (scalar loads) -> ~58 audit. (256,4) cap=64 (R7
// precedent: lands 56 clean when live set fits; R12's 90-reg set spilled).
// Grid 2048 -> 8 blocks/CU co-resident at <=64 VGPR -> 2x R14 occupancy.
// Phantom slot 127: wave 3 chunk s4==124, r==3 -> exact overwrite -3e38.
// ---------------------------------------------------------------------------
__device__ __forceinline__ void extract4(const int (&dk)[6], int r, f16x8 &out)
{
    union { int i[4]; f16x8 v; } u;
    const int p2 = r >> 1;
    #pragma unroll
    for (int i = 0; i < 4; ++i) {
        if (r & 1) {
            unsigned lo32 = (unsigned)dk[p2 + i];
            unsigned hi32 = (unsigned)dk[p2 + i + 1];
            u.i[i] = (int)((lo32 >> 16) | (hi32 << 16)); // v_alignbit
        } else {
            u.i[i] = dk[p2 + i];
        }
    }
    out = u.v;
}

__global__ __launch_bounds__(256, 4) void k_score(
    const _Float16* __restrict__ qf,
    const _Float16* __restrict__ kf,
    const _Float16* __restrict__ wf,
    const float* __restrict__ t2g,
    float* __restrict__ sout)
{
    const int jt = blockIdx.x, it = blockIdx.y, b = blockIdx.z;
    __shared__ __align__(16) _Float16 ldsQ[16][72];
    __shared__ __align__(16) _Float16 ldsK[16][200];
    __shared__ __align__(16) _Float16 ldsW[16][64];
    __shared__ __align__(16) float mbuf[3][256];

    const int tid = threadIdx.x;

    { // zero ldsK (incl. pads): 16*200*2B = 1600 ints
        int* kz = (int*)&ldsK[0][0];
        #pragma unroll
        for (int i = 0; i < 7; ++i) {
            int idx = tid + i * 256;
            if (idx < 1600) kz[idx] = 0;
        }
    }
    if (tid < 128) { // stage Q tile: 16 rows x 64 fp16 = 128 int4
        int r = tid >> 3, c8 = (tid & 7) << 3;
        *(int4v*)&ldsQ[r][c8] =
            *(const int4v*)(qf + ((size_t)(b * 512 + it * 16 + r) * 64 + c8));
    } else { // stage W tile: 16 rows x 64 fp16 = 128 int4
        int u = tid - 128;
        int r = u >> 3, c8 = (u & 7) << 3;
        *(int4v*)&ldsW[r][c8] =
            *(const int4v*)(wf + ((size_t)(b * 512 + jt * 16 + r) * 64 + c8));
    }
    __syncthreads();
    { // stage K reversed: ldsK[r][126-c] = kf[j0+r][c], 16*64 = 1024 elems
        int idx = tid;
        #pragma unroll
        for (int i = 0; i < 4; ++i) {
            int r = idx >> 6, c = idx & 63;
            ldsK[r][126 - c] = kf[(size_t)(b * 512 + jt * 16 + r) * 64 + c];
            idx += 256;
        }
    }
    __syncthreads();

    const int wid = tid >> 6, lane = tid & 63;
    const int lrow = lane & 15, g = lane >> 4;

    f16x8 af[2];
    af[0] = *(const f16x8*)&ldsQ[lrow][g * 8];
    af[1] = *(const f16x8*)&ldsQ[lrow][32 + g * 8];

    // wave-uniform shift base pinned to SGPR -> t2g reads become s_load
    const int s0 = __builtin_amdgcn_readfirstlane(wid * 32);

    float mh[4], se[4];
    #pragma unroll
    for (int p = 0; p < 4; ++p) { mh[p] = -3.0e38f; se[p] = 0.f; }

    for (int s4 = s0; s4 < s0 + 32; s4 += 4) {
        int dk[2][6];
        #pragma unroll
        for (int kc = 0; kc < 2; ++kc) {
            const int off = s4 + kc * 32 + g * 8;
            int4v lo = *(const int4v*)&ldsK[lrow][off];      // fp16 [off, off+8)
            int2v hi = *(const int2v*)&ldsK[lrow][off + 8];  // fp16 [off+8, off+12)
            #pragma unroll
            for (int i = 0; i < 4; ++i) dk[kc][i] = lo[i];
            dk[kc][4] = hi[0];
            dk[kc][5] = hi[1];
        }
        const bool phantom = (s4 == 124);  // wave 3 last chunk holds slot 127
        float av[4][4];
        #pragma unroll
        for (int r = 0; r < 4; ++r) {
            f16x8 b0, b1;
            extract4(dk[0], r, b0);
            extract4(dk[1], r, b1);
            const f32x4 zf = {0.f, 0.f, 0.f, 0.f};
            f32x4 c = __builtin_amdgcn_mfma_f32_16x16x32_f16(af[0], b0, zf, 0, 0, 0);
            c = __builtin_amdgcn_mfma_f32_16x16x32_f16(af[1], b1, c, 0, 0, 0);
            const float t2v = t2g[s4 + r];                   // wave-uniform s_load
            #pragma unroll
            for (int rr = 0; rr < 4; ++rr)
                av[rr][r] = c[rr] * t2v;
        }
        if (phantom) {
            #pragma unroll
            for (int rr = 0; rr < 4; ++rr) av[rr][3] = -3.0e38f;
        }
        #pragma unroll
        for (int rr = 0; rr < 4; ++rr) {
            float A = fmaxf(av[rr][0], av[rr][1]);
            float B = fmaxf(av[rr][2], av[rr][3]);
            float mnew = fmaxf(fmaxf(A, B), mh[rr]);
            float fsc = EXP2R(mh[rr] - mnew);
            float e0 = EXP2R(av[rr][0] - mnew), e1 = EXP2R(av[rr][1] - mnew);
            float e2 = EXP2R(av[rr][2] - mnew), e3 = EXP2R(av[rr][3] - mnew);
            float esum = (e0 + e1) + (e2 + e3);
            se[rr] = fmaf(se[rr], fsc, esum);
            mh[rr] = mnew;
        }
    }

    // wave 0: TA[i][j] = q_i . W_j via 2 MFMAs (all waves hold identical af)
    if (wid == 0) {
        f16x8 bw0 = *(const f16x8*)&ldsW[lrow][g * 8];
        f16x8 bw1 = *(const f16x8*)&ldsW[lrow][32 + g * 8];
        const f32x4 zf = {0.f, 0.f, 0.f, 0.f};
        f32x4 T = __builtin_amdgcn_mfma_f32_16x16x32_f16(af[0], bw0, zf, 0, 0, 0);
        T = __builtin_amdgcn_mfma_f32_16x16x32_f16(af[1], bw1, T, 0, 0, 0);
        #pragma unroll
        for (int rr = 0; rr < 4; ++rr) {
            const int il = g * 4 + rr;
            mbuf[2][il * 16 + lrow] = T[rr];
        }
    }

    // sequential cross-wave merge of (max, sumexp2)
    for (int w = 0; w < 4; ++w) {
        if (wid == w) {
            #pragma unroll
            for (int p = 0; p < 4; ++p) {
                const int il = g * 4 + p;
                const int pi = il * 16 + lrow;
                if (w == 0) {
                    mbuf[0][pi] = mh[p]; mbuf[1][pi] = se[p];
                } else {
                    float Mo = mbuf[0][pi];
                    float M  = fmaxf(Mo, mh[p]);
                    mbuf[0][pi] = M;
                    mbuf[1][pi] = mbuf[1][pi] * EXP2R(Mo - M) + se[p] * EXP2R(mh[p] - M);
                }
            }
        }
        __syncthreads();
    }
    { // write 16x16 tile: one element per thread
        int pi = tid;
        float M = mbuf[0][pi], SE = mbuf[1][pi], TA = mbuf[2][pi];
        float sv = LN2 * (TA - 127.0f * (M + LOG2R(SE)));
        int il = pi >> 4, jl = pi & 15;
        sout[(size_t)(b * 512 + it * 16 + il) * 512 + jt * 16 + jl] = sv;
    }
}

// ---------------------------------------------------------------------------
// Kernel 3: p = s @ v (512-reduction, 4-wave j-split), then out = p @ Wp + bp.
// 1 row per block, 1024 blocks, 256 threads.
// ---------------------------------------------------------------------------
__global__ __launch_bounds__(256) void k_pv(
    const float* __restrict__ s, const float* __restrict__ v,
    const float* __restrict__ Wp, const float* __restrict__ bp,
    float* __restrict__ out)
{
    const int tid = threadIdx.x;
    const int l = tid & 63, w = tid >> 6;     // 4 waves = 4 j-quarters
    const int row = blockIdx.x;               // [0,1024)
    const int b = row >> 9;
    const float* srow = s + (size_t)row * 512 + w * 128;
    const float* vb   = v + (size_t)b * 512 * 64 + (size_t)w * 128 * 64;
    float acc = 0.f;
    #pragma unroll 8
    for (int j = 0; j < 128; ++j)
        acc = fmaf(srow[j], vb[(size_t)j * 64 + l], acc);

    __shared__ float pb[4][64];
    pb[w][l] = acc;
    __syncthreads();

    if (tid < 64) {
        float pr = (pb[0][tid] + pb[1][tid]) + (pb[2][tid] + pb[3][tid]);
        pb[0][tid] = pr;
    }
    __syncthreads();

    if (tid < 64) {
        float o = bp[tid];
        #pragma unroll 8
        for (int jj = 0; jj < 64; ++jj)
            o = fmaf(pb[0][jj], Wp[(size_t)jj * 64 + tid], o);
        out[(size_t)row * 64 + tid] = o;
    }
}

// ---------------------------------------------------------------------------
extern "C" void kernel_launch(void* const* d_in, const int* in_sizes, int n_in,
                              void* d_out, int out_size, void* d_ws, size_t ws_size,
                              hipStream_t stream)
{
    const float* x  = (const float*)d_in[0];
    const float* Wq = (const float*)d_in[1];
    const float* bq = (const float*)d_in[2];
    const float* Wk = (const float*)d_in[3];
    const float* bk = (const float*)d_in[4];
    const float* Wv = (const float*)d_in[5];
    const float* bv = (const float*)d_in[6];
    const float* Wp = (const float*)d_in[7];
    const float* bp = (const float*)d_in[8];
    float* out = (float*)d_out;

    char* ws = (char*)d_ws;
    _Float16* qf = (_Float16*)(ws + 0 * 131072);
    _Float16* kf = (_Float16*)(ws + 1 * 131072);
    _Float16* wfp = (_Float16*)(ws + 2 * 131072);
    float* vws = (float*)(ws + 3 * 131072);                 // 262144 B
    float* sws = (float*)(ws + 3 * 131072 + 262144);        // 2097152 B
    float* t2g = (float*)(ws + 3 * 131072 + 262144 + 2097152); // 512 B

    k_qkv<<<dim3(256), dim3(384), 0, stream>>>(x, Wq, bq, Wk, bk, Wv, bv,
                                               qf, kf, wfp, vws, t2g);
    k_score<<<dim3(32, 32, 2), dim3(256), 0, stream>>>(qf, kf, wfp, t2g, sws);
    k_pv<<<dim3(1024), dim3(256), 0, stream>>>(sws, vws, Wp, bp, out);
}

// Round 17
// 46.069 us; speedup vs baseline: 1.4061x; 1.4061x over previous
//
#include <hip/hip_runtime.h>
#include <hip/hip_bf16.h>

typedef float f32x4 __attribute__((ext_vector_type(4)));
typedef _Float16 f16x8 __attribute__((ext_vector_type(8)));
typedef int   int4v  __attribute__((ext_vector_type(4)));

#define LOG2E 1.44269504088896340736f
#define LN2   0.693147180559945309417f
#define EXP2R(x) __builtin_amdgcn_exp2f(x)   // raw v_exp_f32: args <=0, underflow->0 correct
#define LOG2R(x) __builtin_amdgcn_logf(x)    // raw v_log_f32 (log2)

// ---------------------------------------------------------------------------
// Kernel 1: q,k (-> fp16), v (f32), W[row,f] = sum_d t2[126-f-d]*k[row,d] (fp16).
// 4 rows per block, 256 blocks, 384 threads = 6 waves.
// ---------------------------------------------------------------------------
__global__ __launch_bounds__(384) void k_qkv(
    const float* __restrict__ x,
    const float* __restrict__ Wq, const float* __restrict__ bq,
    const float* __restrict__ Wk, const float* __restrict__ bk,
    const float* __restrict__ Wv, const float* __restrict__ bv,
    _Float16* __restrict__ qf, _Float16* __restrict__ kf,
    _Float16* __restrict__ wf, float* __restrict__ vout)
{
    const int row0 = blockIdx.x * 4;           // rows = b*512 + i, [0,1024)
    __shared__ __align__(16) float xr[4][512];
    __shared__ __align__(16) float klds[4][64];
    __shared__ __align__(16) float t2s[128];
    const int tid = threadIdx.x;

    for (int i = tid; i < 512; i += 384)       // 4 rows * 512 f32 = 512 float4
        ((f32x4*)&xr[0][0])[i] = ((const f32x4*)(x + (size_t)row0 * 512))[i];
    if (tid < 128) { // scaler table by shift s; t2s[127] = 0
        int s = tid, t = 126 - s;
        float nd = (t < 64) ? (float)(t + 1) : (float)(127 - t);
        t2s[s] = (s < 127) ? ((float)(t + 2) / nd) * LOG2E : 0.0f;
    }
    __syncthreads();

    const int w = tid >> 6, f = tid & 63;
    const int m = w >> 1, rp = (w & 1) * 2;    // matrix, row-pair base
    const float* W    = (m == 0) ? Wq : (m == 1) ? Wk : Wv;
    const float bias  = ((m == 0) ? bq : (m == 1) ? bk : bv)[f];
    float a0 = bias, a1 = bias;
    #pragma unroll 16
    for (int d = 0; d < 512; ++d) {
        float wv = W[(size_t)d * 64 + f];
        a0 = fmaf(xr[rp][d], wv, a0);
        a1 = fmaf(xr[rp + 1][d], wv, a1);
    }
    if (m == 0) {
        qf[(size_t)(row0 + rp) * 64 + f]     = (_Float16)a0;
        qf[(size_t)(row0 + rp + 1) * 64 + f] = (_Float16)a1;
    } else if (m == 1) {
        kf[(size_t)(row0 + rp) * 64 + f]     = (_Float16)a0;
        kf[(size_t)(row0 + rp + 1) * 64 + f] = (_Float16)a1;
        klds[rp][f] = a0; klds[rp + 1][f] = a1;
    } else {
        vout[(size_t)(row0 + rp) * 64 + f]     = a0;
        vout[(size_t)(row0 + rp + 1) * 64 + f] = a1;
    }
    __syncthreads();
    if (m == 2) { // wf[row,f] = sum_d t2s[126-f-d]*k[row,d], rows rp..rp+1
        float w0 = 0.f, w1 = 0.f;
        #pragma unroll 8
        for (int d = 0; d < 64; ++d) {
            float t = t2s[126 - f - d];
            w0 = fmaf(t, klds[rp][d], w0);
            w1 = fmaf(t, klds[rp + 1][d], w1);
        }
        wf[(size_t)(row0 + rp) * 64 + f]     = (_Float16)w0;
        wf[(size_t)(row0 + rp + 1) * 64 + f] = (_Float16)w1;
    }
}

// ---------------------------------------------------------------------------
// Kernel 2: per (b, i-tile 32, j-tile 16): 4 waves x 32 shift-slots (slot 127
// phantom, masked by additive bias). FINAL CONFIG (round 14, 46.2us, absmax
// 2048): batch av[4][8] scalar tree (8 independent v_exp pipeline) at
// __launch_bounds__(256,2) so the allocator may use up to 128 VGPR — the
// ~80-95-reg live set then fits with NO spill.
// Experimental map (do not revisit):
//  - (256,4) or tighter on ANY shape of this kernel -> allocator caps 64 and
//    spills 30-400 MB scratch (R5/R10/R12/R16); live set >= ~80 in all shapes.
//  - per-term online update (R13): -16us (serial exp dependency chains).
//  - f32x4 packed softmax tail (R10/R11): absmax 4864/24576, closed.
//  - scalar-pipe t2 / op micro-opts (R15): neutral — latency-bound, not
//    op-bound, at 4 waves/SIMD.
// ---------------------------------------------------------------------------
__device__ __forceinline__ void extract8(const int (&dk)[8], int r, f16x8 &out)
{
    union { int i[4]; f16x8 v; } u;
    const int p2 = r >> 1;
    #pragma unroll
    for (int i = 0; i < 4; ++i) {
        if (r & 1) {
            unsigned lo32 = (unsigned)dk[p2 + i];
            unsigned hi32 = (unsigned)dk[p2 + i + 1];
            u.i[i] = (int)((lo32 >> 16) | (hi32 << 16)); // v_alignbit
        } else {
            u.i[i] = dk[p2 + i];
        }
    }
    out = u.v;
}

__global__ __launch_bounds__(256, 2) void k_score(
    const _Float16* __restrict__ qf,
    const _Float16* __restrict__ kf,
    const _Float16* __restrict__ wf,
    float* __restrict__ sout)
{
    const int jt = blockIdx.x, it = blockIdx.y, b = blockIdx.z;
    __shared__ __align__(16) _Float16 ldsQ[32][72];
    __shared__ __align__(16) _Float16 ldsK[16][200];
    __shared__ __align__(16) _Float16 ldsW[16][64];
    __shared__ __align__(16) float t2[128];
    __shared__ __align__(16) float tb[128];
    __shared__ __align__(16) float mbuf[3][512];

    const int tid = threadIdx.x;

    { // zero ldsK (incl. pads): 16*200*2B = 1600 ints
        int* kz = (int*)&ldsK[0][0];
        #pragma unroll
        for (int i = 0; i < 7; ++i) {
            int idx = tid + i * 256;
            if (idx < 1600) kz[idx] = 0;
        }
    }
    { // stage Q tile: 32 rows x 64 fp16 = 256 int4
        int r = tid >> 3, c8 = (tid & 7) << 3;
        *(int4v*)&ldsQ[r][c8] =
            *(const int4v*)(qf + ((size_t)(b * 512 + it * 32 + r) * 64 + c8));
    }
    if (tid >= 128 && tid < 256) { // stage W tile: 16 rows x 64 fp16 = 128 int4
        int u = tid - 128;
        int r = u >> 3, c8 = (u & 7) << 3;
        *(int4v*)&ldsW[r][c8] =
            *(const int4v*)(wf + ((size_t)(b * 512 + jt * 16 + r) * 64 + c8));
    }
    if (tid < 128) { // scaler + mask-bias tables (slot 127 is phantom)
        int s = tid, t = 126 - s;
        float nd = (t < 64) ? (float)(t + 1) : (float)(127 - t);
        t2[s] = (s < 127) ? ((float)(t + 2) / nd) * LOG2E : 0.0f;
        tb[s] = (s < 127) ? 0.0f : -1.0e38f;
    }
    __syncthreads();
    { // stage K reversed: ldsK[r][126-c] = kf[j0+r][c], 16*64 = 1024 elems
        int idx = tid;
        #pragma unroll
        for (int i = 0; i < 4; ++i) {
            int r = idx >> 6, c = idx & 63;
            ldsK[r][126 - c] = kf[(size_t)(b * 512 + jt * 16 + r) * 64 + c];
            idx += 256;
        }
    }
    __syncthreads();

    const int wid = tid >> 6, lane = tid & 63;
    const int lrow = lane & 15, g = lane >> 4;

    f16x8 af[2][2];
    #pragma unroll
    for (int ih = 0; ih < 2; ++ih)
        #pragma unroll
        for (int kc = 0; kc < 2; ++kc)
            af[ih][kc] = *(const f16x8*)&ldsQ[ih * 16 + lrow][kc * 32 + g * 8];

    const int s0 = wid * 32;       // 32 shifts per wave

    float mh[8], se[8];
    #pragma unroll
    for (int p = 0; p < 8; ++p) { mh[p] = -3.0e38f; se[p] = 0.f; }

    for (int s8 = s0; s8 < s0 + 32; s8 += 8) {
        f32x4 tt0 = *(const f32x4*)&t2[s8];
        f32x4 tt1 = *(const f32x4*)&t2[s8 + 4];
        f32x4 tv0 = *(const f32x4*)&tb[s8];
        f32x4 tv1 = *(const f32x4*)&tb[s8 + 4];
        int dk[2][8];
        #pragma unroll
        for (int kc = 0; kc < 2; ++kc) {
            const int off = s8 + kc * 32 + g * 8;
            const int4v* kp = (const int4v*)&ldsK[lrow][off];
            int4v lo = kp[0];
            int4v hi = kp[1];
            #pragma unroll
            for (int i = 0; i < 4; ++i) {
                dk[kc][i]     = lo[i];
                dk[kc][4 + i] = hi[i];
            }
        }
        #pragma unroll
        for (int ih = 0; ih < 2; ++ih) {
            float av[4][8];
            #pragma unroll
            for (int r = 0; r < 8; ++r) {
                f16x8 b0, b1;
                extract8(dk[0], r, b0);
                extract8(dk[1], r, b1);
                const f32x4 zf = {0.f, 0.f, 0.f, 0.f};
                f32x4 c = __builtin_amdgcn_mfma_f32_16x16x32_f16(af[ih][0], b0, zf, 0, 0, 0);
                c = __builtin_amdgcn_mfma_f32_16x16x32_f16(af[ih][1], b1, c, 0, 0, 0);
                const float t2v = (r < 4) ? tt0[r & 3] : tt1[r & 3];
                const float tbv = (r < 4) ? tv0[r & 3] : tv1[r & 3];
                #pragma unroll
                for (int rr = 0; rr < 4; ++rr)
                    av[rr][r] = fmaf(c[rr], t2v, tbv);
            }
            #pragma unroll
            for (int rr = 0; rr < 4; ++rr) {
                const int p = ih * 4 + rr;
                float A = fmaxf(fmaxf(av[rr][0], av[rr][1]), av[rr][2]);
                float B = fmaxf(fmaxf(av[rr][3], av[rr][4]), av[rr][5]);
                float C = fmaxf(fmaxf(av[rr][6], av[rr][7]), mh[p]);
                float mnew = fmaxf(fmaxf(A, B), C);
                float fsc = EXP2R(mh[p] - mnew);
                float e0 = EXP2R(av[rr][0] - mnew), e1 = EXP2R(av[rr][1] - mnew);
                float e2 = EXP2R(av[rr][2] - mnew), e3 = EXP2R(av[rr][3] - mnew);
                float e4 = EXP2R(av[rr][4] - mnew), e5 = EXP2R(av[rr][5] - mnew);
                float e6 = EXP2R(av[rr][6] - mnew), e7 = EXP2R(av[rr][7] - mnew);
                float esum = ((e0 + e1) + (e2 + e3)) + ((e4 + e5) + (e6 + e7));
                se[p] = fmaf(se[p], fsc, esum);
                mh[p] = mnew;
            }
        }
    }

    // wave 0: TA[i][j] = q_i . W_j via 4 MFMAs (all waves hold identical af)
    if (wid == 0) {
        f16x8 bw0 = *(const f16x8*)&ldsW[lrow][g * 8];
        f16x8 bw1 = *(const f16x8*)&ldsW[lrow][32 + g * 8];
        #pragma unroll
        for (int ih = 0; ih < 2; ++ih) {
            const f32x4 zf = {0.f, 0.f, 0.f, 0.f};
            f32x4 T = __builtin_amdgcn_mfma_f32_16x16x32_f16(af[ih][0], bw0, zf, 0, 0, 0);
            T = __builtin_amdgcn_mfma_f32_16x16x32_f16(af[ih][1], bw1, T, 0, 0, 0);
            #pragma unroll
            for (int rr = 0; rr < 4; ++rr) {
                const int il = ih * 16 + g * 4 + rr;
                mbuf[2][il * 16 + lrow] = T[rr];
            }
        }
    }

    // sequential cross-wave merge of (max, sumexp2)
    for (int w = 0; w < 4; ++w) {
        if (wid == w) {
            #pragma unroll
            for (int p = 0; p < 8; ++p) {
                const int ih = p >> 2, rr = p & 3;
                const int il = ih * 16 + g * 4 + rr;
                const int pi = il * 16 + lrow;
                if (w == 0) {
                    mbuf[0][pi] = mh[p]; mbuf[1][pi] = se[p];
                } else {
                    float Mo = mbuf[0][pi];
                    float M  = fmaxf(Mo, mh[p]);
                    mbuf[0][pi] = M;
                    mbuf[1][pi] = mbuf[1][pi] * EXP2R(Mo - M) + se[p] * EXP2R(mh[p] - M);
                }
            }
        }
        __syncthreads();
    }
    #pragma unroll
    for (int k2 = 0; k2 < 2; ++k2) {
        int pi = tid + k2 * 256;
        float M = mbuf[0][pi], SE = mbuf[1][pi], TA = mbuf[2][pi];
        float sv = LN2 * (TA - 127.0f * (M + LOG2R(SE)));
        int il = pi >> 4, jl = pi & 15;
        sout[(size_t)(b * 512 + it * 32 + il) * 512 + jt * 16 + jl] = sv;
    }
}

// ---------------------------------------------------------------------------
// Kernel 3: p = s @ v (512-reduction, 4-wave j-split), then out = p @ Wp + bp.
// 1 row per block, 1024 blocks, 256 threads.
// ---------------------------------------------------------------------------
__global__ __launch_bounds__(256) void k_pv(
    const float* __restrict__ s, const float* __restrict__ v,
    const float* __restrict__ Wp, const float* __restrict__ bp,
    float* __restrict__ out)
{
    const int tid = threadIdx.x;
    const int l = tid & 63, w = tid >> 6;     // 4 waves = 4 j-quarters
    const int row = blockIdx.x;               // [0,1024)
    const int b = row >> 9;
    const float* srow = s + (size_t)row * 512 + w * 128;
    const float* vb   = v + (size_t)b * 512 * 64 + (size_t)w * 128 * 64;
    float acc = 0.f;
    #pragma unroll 8
    for (int j = 0; j < 128; ++j)
        acc = fmaf(srow[j], vb[(size_t)j * 64 + l], acc);

    __shared__ float pb[4][64];
    pb[w][l] = acc;
    __syncthreads();

    if (tid < 64) {
        float pr = (pb[0][tid] + pb[1][tid]) + (pb[2][tid] + pb[3][tid]);
        pb[0][tid] = pr;
    }
    __syncthreads();

    if (tid < 64) {
        float o = bp[tid];
        #pragma unroll 8
        for (int jj = 0; jj < 64; ++jj)
            o = fmaf(pb[0][jj], Wp[(size_t)jj * 64 + tid], o);
        out[(size_t)row * 64 + tid] = o;
    }
}

// ---------------------------------------------------------------------------
extern "C" void kernel_launch(void* const* d_in, const int* in_sizes, int n_in,
                              void* d_out, int out_size, void* d_ws, size_t ws_size,
                              hipStream_t stream)
{
    const float* x  = (const float*)d_in[0];
    const float* Wq = (const float*)d_in[1];
    const float* bq = (const float*)d_in[2];
    const float* Wk = (const float*)d_in[3];
    const float* bk = (const float*)d_in[4];
    const float* Wv = (const float*)d_in[5];
    const float* bv = (const float*)d_in[6];
    const float* Wp = (const float*)d_in[7];
    const float* bp = (const float*)d_in[8];
    float* out = (float*)d_out;

    char* ws = (char*)d_ws;
    _Float16* qf = (_Float16*)(ws + 0 * 131072);
    _Float16* kf = (_Float16*)(ws + 1 * 131072);
    _Float16* wfp = (_Float16*)(ws + 2 * 131072);
    float* vws = (float*)(ws + 3 * 131072);                 // 262144 B
    float* sws = (float*)(ws + 3 * 131072 + 262144);        // 2097152 B

    k_qkv<<<dim3(256), dim3(384), 0, stream>>>(x, Wq, bq, Wk, bk, Wv, bv,
                                               qf, kf, wfp, vws);
    k_score<<<dim3(32, 16, 2), dim3(256), 0, stream>>>(qf, kf, wfp, sws);
    k_pv<<<dim3(1024), dim3(256), 0, stream>>>(sws, vws, Wp, bp, out);
}